// Round 21
// baseline (385.134 us; speedup 1.0000x reference)
//
#include <hip/hip_runtime.h>
#include <stdint.h>

#define EFFECT_DIM 758
#define ADD_DIM 10
#define EMBED_DIM 768
#define NCOLS 95000
#define NSYN 8
#define NROWS 1024
#define NT256 372            // ceil(95000/256)
#define TILE_B 32768         // 256x64 bf16 A tile, fragment-ordered

typedef __attribute__((ext_vector_type(8))) __bf16 bf16x8;
typedef __attribute__((ext_vector_type(16))) float f32x16;
typedef __attribute__((ext_vector_type(4))) uint32_t u32x4;

// Fragment order: tile = [kk 0..3][grp 0..7][lane 0..63] x 16B.
// frag(kk,grp) = 1KB; lane = (row&31) + (khalf8<<5); 16B = 8 consecutive k.
// ds_read_b128 + per-n (1n/thread) ds_write: 0 bank conflicts (R10-R16).

static __device__ __forceinline__ uint32_t pack2(float a, float b) {
  uint32_t r;
  asm("v_cvt_pk_bf16_f32 %0, %1, %2" : "=v"(r) : "v"(a), "v"(b));
  return r;
}

#define GLOAD16(src, dst)                                                   \
  __builtin_amdgcn_global_load_lds(                                         \
      (const __attribute__((address_space(1))) uint32_t*)(src),             \
      (__attribute__((address_space(3))) uint32_t*)(dst), 16, 0, 0)

// ---------------------------------------------------------------------------
// Kernel 1: VirtualEmbedding -> bf16 A tiles (4 m-tiles x 12 ks), frag order.
// (verified R9-R20)
// ---------------------------------------------------------------------------
__global__ __launch_bounds__(256) void emb_kernel(
    const int* __restrict__ ids, const float* __restrict__ W_emb,
    const float* __restrict__ padding, const int* __restrict__ syn_table,
    const int* __restrict__ syn_mask, char* __restrict__ ws)
{
  const int l = blockIdx.x;
  const int t = threadIdx.x;
  const int id = ids[l];
  int sid[NSYN];
  int msk[NSYN];
#pragma unroll
  for (int k = 0; k < NSYN; ++k) {
    sid[k] = syn_table[id * NSYN + k];
    msk[k] = syn_mask[id * NSYN + k];
  }

  double p[9] = {0, 0, 0, 0, 0, 0, 0, 0, 0};
  for (int d = t; d < EFFECT_DIM; d += 256) {
    p[0] += (double)W_emb[(size_t)id * EFFECT_DIM + d];
#pragma unroll
    for (int k = 0; k < NSYN; ++k)
      p[k + 1] += (double)W_emb[(size_t)sid[k] * EFFECT_DIM + d];
  }

  __shared__ double s_red[9][4];
  const int w = t >> 6;
#pragma unroll
  for (int k = 0; k < 9; ++k) {
    double v = p[k];
#pragma unroll
    for (int off = 32; off > 0; off >>= 1) v += __shfl_down(v, off, 64);
    if ((t & 63) == 0) s_red[k][w] = v;
  }
  __syncthreads();

  const double isum = s_red[0][0] + s_red[0][1] + s_red[0][2] + s_red[0][3];
  float coef[NSYN];
#pragma unroll
  for (int k = 0; k < NSYN; ++k) {
    double ss = s_red[k + 1][0] + s_red[k + 1][1] + s_red[k + 1][2] + s_red[k + 1][3];
    coef[k] = msk[k] ? (float)(isum / ss) : 0.0f;
  }

  const int r = l & 255;
  char* wbase = ws + (size_t)(l >> 8) * (12 * TILE_B);

  for (int j = t; j < 384; j += 256) {
    const int d0 = 2 * j;
    float v0, v1;
    if (d0 < EFFECT_DIM) {
      const float* bp = W_emb + (size_t)id * EFFECT_DIM + d0;
      v0 = bp[0];
      v1 = bp[1];
#pragma unroll
      for (int k = 0; k < NSYN; ++k) {
        const float* sp = W_emb + (size_t)sid[k] * EFFECT_DIM + d0;
        v0 = fmaf(coef[k], sp[0], v0);
        v1 = fmaf(coef[k], sp[1], v1);
      }
    } else {
      v0 = padding[l * ADD_DIM + (d0 - EFFECT_DIM)];
      v1 = padding[l * ADD_DIM + (d0 + 1 - EFFECT_DIM)];
    }
    const int ks   = j >> 5;
    const int jl   = j & 31;
    const int kk   = jl >> 3;
    const int byte = (jl & 7) * 4;
    const int lane = (r & 31) + ((byte >> 4) << 5);
    *(uint32_t*)(wbase + ks * TILE_B + kk * 8192 + (r >> 5) * 1024 +
                 lane * 16 + (byte & 15)) = pack2(v0, v1);
  }
}

// ---------------------------------------------------------------------------
// Kernel 2 (R21 = exact R16 + nontemporal epilogue): 256x256 tile, 512 thr,
// 8 waves (2m x 4n), wave 128x64, acc[4][2]. LDS 128KB = 2 sets x
// [A 32K][B 32K], frag-ordered. Per K-step T (computing set cs = T&1):
//   AGLD(cs^1, T+1)          // 4 gload_lds, OLDEST in vm queue
//   BLOAD(brNext, T+2)       // 32 f32 scalar loads, in flight 2 steps
//   4 x {6 ds_read_b128 + 8 MFMA (setprio)}
//   BSTORE(brCur = B(T+1))   // loaded a FULL step ago -> retired, no stall
//   lgkmcnt(0); vmcnt(32)    // A(T+1) confirmed (older), B(T+2) in flight
//   s_barrier
// NT stores in epilogue: out is write-once; keep W_rev panels (shared by
// 4 mt-siblings per XCD) resident in L2.
// ---------------------------------------------------------------------------
__global__ __launch_bounds__(512, 2) void gemm_fused(
    const float* __restrict__ Wrev, const char* __restrict__ Abuf,
    float* __restrict__ out)
{
  extern __shared__ char lds[];  // set s at s*65536: [A 32K][B 32K]
  const int t = threadIdx.x;
  const int l = t & 63;
  const int w = t >> 6;
  const int wm = w >> 2;       // 0..1
  const int wn = w & 3;        // 0..3

  const int wgid = blockIdx.x;            // 1488 = 8 x 186
  const int xcd  = wgid & 7;
  const int work = xcd * 186 + (wgid >> 3);
  const int mt = work & 3;
  const int nt = work >> 2;
  const int n0 = nt * 256;

  const char* asrc = Abuf + (size_t)mt * (12 * TILE_B);

  // B staging role: thread owns col sn (0..255), k-rows kg*32..+31
  const int sn = t & 255;
  const int kg = t >> 8;       // 0..1
  const int gn = n0 + sn;
  const bool valid = gn < NCOLS;

  float br0[32], br1[32];

#define AGLD(s, ksi)                                                         \
  {                                                                          \
    _Pragma("unroll") for (int kk = 0; kk < 4; ++kk)                         \
      GLOAD16(asrc + (ksi)*TILE_B + kk*8192 + t*16,                          \
              lds + (s)*65536 + kk*8192 + w*1024);                           \
  }

#define BLOAD(br, ksi)                                                       \
  {                                                                          \
    const float* p = Wrev + (size_t)((ksi)*64 + kg*32) * NCOLS + gn;         \
    _Pragma("unroll") for (int j = 0; j < 32; ++j)                           \
      br[j] = valid ? p[(size_t)j * NCOLS] : 0.0f;                           \
  }

#define BSTORE(br, s)                                                        \
  {                                                                          \
    _Pragma("unroll") for (int c = 0; c < 2; ++c) {                          \
      u32x4 u0, u1;                                                          \
      _Pragma("unroll") for (int j = 0; j < 4; ++j) {                        \
        u0[j] = pack2(br[c*16 + 2*j],     br[c*16 + 2*j + 1]);               \
        u1[j] = pack2(br[c*16 + 8 + 2*j], br[c*16 + 9 + 2*j]);               \
      }                                                                      \
      char* bb = lds + (s)*65536 + 32768 + (kg*2 + c)*8192 + (sn>>5)*1024;   \
      *(u32x4*)(bb + (sn & 31)*16) = u0;                                     \
      *(u32x4*)(bb + ((sn & 31) + 32)*16) = u1;                              \
    }                                                                        \
  }

#define COMPUTE(cs)                                                          \
  {                                                                          \
    const char* aw = lds + (cs)*65536 + (wm*4)*1024 + l*16;                  \
    const char* bw = lds + (cs)*65536 + 32768 + (wn*2)*1024 + l*16;          \
    _Pragma("unroll") for (int p = 0; p < 4; ++p) {                          \
      bf16x8 a[4], b[2];                                                     \
      _Pragma("unroll") for (int mr = 0; mr < 4; ++mr)                       \
        a[mr] = *(const bf16x8*)(aw + p*8192 + mr*1024);                     \
      _Pragma("unroll") for (int nr = 0; nr < 2; ++nr)                       \
        b[nr] = *(const bf16x8*)(bw + p*8192 + nr*1024);                     \
      __builtin_amdgcn_s_setprio(1);                                         \
      _Pragma("unroll") for (int mr = 0; mr < 4; ++mr)                       \
        _Pragma("unroll") for (int nr = 0; nr < 2; ++nr)                     \
          acc[mr][nr] = __builtin_amdgcn_mfma_f32_32x32x16_bf16(             \
              a[mr], b[nr], acc[mr][nr], 0, 0, 0);                           \
      __builtin_amdgcn_s_setprio(0);                                         \
    }                                                                        \
  }

  // one full pipelined step: compute set cs / tile TT; prep set cs^1
#define STEP(cs, TT, brCur, brNext)                                          \
  {                                                                          \
    if ((TT) + 1 < 12) AGLD((cs) ^ 1, (TT) + 1);       /* oldest in queue */ \
    if ((TT) + 2 < 12) BLOAD(brNext, (TT) + 2);                              \
    __builtin_amdgcn_sched_barrier(0);                                       \
    COMPUTE(cs);                                                             \
    __builtin_amdgcn_sched_barrier(0);                                       \
    if ((TT) + 1 < 12) {                                                     \
      BSTORE(brCur, (cs) ^ 1);         /* brCur loaded a full step ago */    \
      asm volatile("s_waitcnt lgkmcnt(0)" ::: "memory");                     \
      if ((TT) + 2 < 12) asm volatile("s_waitcnt vmcnt(32)" ::: "memory");   \
      else               asm volatile("s_waitcnt vmcnt(0)" ::: "memory");    \
      __builtin_amdgcn_sched_barrier(0);                                     \
      __builtin_amdgcn_s_barrier();                                          \
    }                                                                        \
  }

  // prologue: tile 0 -> set 0; preload B(1) into br0
  AGLD(0, 0);
  BLOAD(br0, 0);
  BSTORE(br0, 0);   // compiler waits br0 (drains A(0) too — older)
  BLOAD(br0, 1);
  asm volatile("s_waitcnt lgkmcnt(0)" ::: "memory");
  __builtin_amdgcn_sched_barrier(0);
  __builtin_amdgcn_s_barrier();

  f32x16 acc[4][2] = {};

#pragma unroll
  for (int Ti = 0; Ti < 6; ++Ti) {
    STEP(0, 2 * Ti,     br0, br1);
    STEP(1, 2 * Ti + 1, br1, br0);
  }
#undef STEP
#undef COMPUTE
#undef AGLD
#undef BLOAD
#undef BSTORE

  // epilogue (nontemporal): col=lane&31, row=(reg&3)+8*(reg>>2)+4*(lane>>5)
  const int lh = l >> 5;
#pragma unroll
  for (int nr = 0; nr < 2; ++nr) {
    const int gc = n0 + wn * 64 + nr * 32 + (l & 31);
    if (gc < NCOLS) {
#pragma unroll
      for (int mr = 0; mr < 4; ++mr)
#pragma unroll
        for (int reg = 0; reg < 16; ++reg) {
          const int row = mt * 256 + wm * 128 + mr * 32 +
                          (reg & 3) + 8 * (reg >> 2) + 4 * lh;
          __builtin_nontemporal_store(acc[mr][nr][reg],
                                      &out[(size_t)row * NCOLS + gc]);
        }
    }
  }
}

extern "C" void kernel_launch(void* const* d_in, const int* in_sizes, int n_in,
                              void* d_out, int out_size, void* d_ws, size_t ws_size,
                              hipStream_t stream) {
  const int*   ids       = (const int*)d_in[0];
  const float* W_emb     = (const float*)d_in[1];
  const float* W_rev     = (const float*)d_in[2];
  const float* padding   = (const float*)d_in[3];
  const int*   syn_table = (const int*)d_in[4];
  const int*   syn_mask  = (const int*)d_in[5];
  float* out = (float*)d_out;
  char*  ws  = (char*)d_ws;

  // A tiles in ws[0, 1.5MB); conv pass deleted
  hipLaunchKernelGGL(emb_kernel, dim3(NROWS), dim3(256), 0, stream,
                     ids, W_emb, padding, syn_table, syn_mask, ws);

  // 1488 blocks: 4 m-tiles x 372 n-tiles = 8 XCDs x 186 (bijective)
  hipLaunchKernelGGL(gemm_fused, dim3(4 * NT256), dim3(512), 131072, stream,
                     W_rev, ws, out);
}

// Round 22
// 328.809 us; speedup vs baseline: 1.1713x; 1.1713x over previous
//
#include <hip/hip_runtime.h>
#include <stdint.h>

#define EFFECT_DIM 758
#define ADD_DIM 10
#define EMBED_DIM 768
#define NCOLS 95000
#define NSYN 8
#define NROWS 1024
#define NT256 372            // ceil(95000/256)
#define TILE_B 32768         // 256x64 bf16 A tile, fragment-ordered

typedef __attribute__((ext_vector_type(8))) __bf16 bf16x8;
typedef __attribute__((ext_vector_type(16))) float f32x16;
typedef __attribute__((ext_vector_type(4))) uint32_t u32x4;

// Fragment order: tile = [kk 0..3][grp 0..7][lane 0..63] x 16B.
// frag(kk,grp) = 1KB; lane = (row&31) + (khalf8<<5); 16B = 8 consecutive k.
// ds_read_b128 + per-n (1n/thread) ds_write: 0 bank conflicts (R10-R16).
// R16 configuration: best measured bench total (330.30 us). R17-R21
// single-variable probes (float4/float2 B, NT stores, m201 phases,
// 1-wave/SIMD) all tied or regressed — this is the ledger optimum.

static __device__ __forceinline__ uint32_t pack2(float a, float b) {
  uint32_t r;
  asm("v_cvt_pk_bf16_f32 %0, %1, %2" : "=v"(r) : "v"(a), "v"(b));
  return r;
}

#define GLOAD16(src, dst)                                                   \
  __builtin_amdgcn_global_load_lds(                                         \
      (const __attribute__((address_space(1))) uint32_t*)(src),             \
      (__attribute__((address_space(3))) uint32_t*)(dst), 16, 0, 0)

// ---------------------------------------------------------------------------
// Kernel 1: VirtualEmbedding -> bf16 A tiles (4 m-tiles x 12 ks), frag order.
// (verified R9-R21)
// ---------------------------------------------------------------------------
__global__ __launch_bounds__(256) void emb_kernel(
    const int* __restrict__ ids, const float* __restrict__ W_emb,
    const float* __restrict__ padding, const int* __restrict__ syn_table,
    const int* __restrict__ syn_mask, char* __restrict__ ws)
{
  const int l = blockIdx.x;
  const int t = threadIdx.x;
  const int id = ids[l];
  int sid[NSYN];
  int msk[NSYN];
#pragma unroll
  for (int k = 0; k < NSYN; ++k) {
    sid[k] = syn_table[id * NSYN + k];
    msk[k] = syn_mask[id * NSYN + k];
  }

  double p[9] = {0, 0, 0, 0, 0, 0, 0, 0, 0};
  for (int d = t; d < EFFECT_DIM; d += 256) {
    p[0] += (double)W_emb[(size_t)id * EFFECT_DIM + d];
#pragma unroll
    for (int k = 0; k < NSYN; ++k)
      p[k + 1] += (double)W_emb[(size_t)sid[k] * EFFECT_DIM + d];
  }

  __shared__ double s_red[9][4];
  const int w = t >> 6;
#pragma unroll
  for (int k = 0; k < 9; ++k) {
    double v = p[k];
#pragma unroll
    for (int off = 32; off > 0; off >>= 1) v += __shfl_down(v, off, 64);
    if ((t & 63) == 0) s_red[k][w] = v;
  }
  __syncthreads();

  const double isum = s_red[0][0] + s_red[0][1] + s_red[0][2] + s_red[0][3];
  float coef[NSYN];
#pragma unroll
  for (int k = 0; k < NSYN; ++k) {
    double ss = s_red[k + 1][0] + s_red[k + 1][1] + s_red[k + 1][2] + s_red[k + 1][3];
    coef[k] = msk[k] ? (float)(isum / ss) : 0.0f;
  }

  const int r = l & 255;
  char* wbase = ws + (size_t)(l >> 8) * (12 * TILE_B);

  for (int j = t; j < 384; j += 256) {
    const int d0 = 2 * j;
    float v0, v1;
    if (d0 < EFFECT_DIM) {
      const float* bp = W_emb + (size_t)id * EFFECT_DIM + d0;
      v0 = bp[0];
      v1 = bp[1];
#pragma unroll
      for (int k = 0; k < NSYN; ++k) {
        const float* sp = W_emb + (size_t)sid[k] * EFFECT_DIM + d0;
        v0 = fmaf(coef[k], sp[0], v0);
        v1 = fmaf(coef[k], sp[1], v1);
      }
    } else {
      v0 = padding[l * ADD_DIM + (d0 - EFFECT_DIM)];
      v1 = padding[l * ADD_DIM + (d0 + 1 - EFFECT_DIM)];
    }
    const int ks   = j >> 5;
    const int jl   = j & 31;
    const int kk   = jl >> 3;
    const int byte = (jl & 7) * 4;
    const int lane = (r & 31) + ((byte >> 4) << 5);
    *(uint32_t*)(wbase + ks * TILE_B + kk * 8192 + (r >> 5) * 1024 +
                 lane * 16 + (byte & 15)) = pack2(v0, v1);
  }
}

// ---------------------------------------------------------------------------
// Kernel 2 (R22 = exact R16 revert, the measured optimum): 256x256 tile,
// 512 thr, 8 waves (2m x 4n), wave 128x64, acc[4][2]. LDS 128KB = 2 sets x
// [A 32K][B 32K], frag-ordered. Per K-step T (computing set cs = T&1):
//   AGLD(cs^1, T+1)          // 4 gload_lds, OLDEST in vm queue
//   BLOAD(brNext, T+2)       // 32 f32 loads, stay in flight 2 steps
//   4 x {6 ds_read_b128 + 8 MFMA (setprio)}
//   BSTORE(brCur = B(T+1))   // loaded a FULL step ago -> retired, no stall
//   lgkmcnt(0); vmcnt(32)    // A(T+1) confirmed (older), B(T+2) in flight
//   s_barrier
// 12 barriers, 12 counted waits. Conv pass deleted. T1 remap 1488 = 8x186:
// 4 mt-siblings share each W_rev panel on one XCD (f32 B read ~once).
// Cached (default) epilogue stores — NT regressed 17% (R21).
// ---------------------------------------------------------------------------
__global__ __launch_bounds__(512, 2) void gemm_fused(
    const float* __restrict__ Wrev, const char* __restrict__ Abuf,
    float* __restrict__ out)
{
  extern __shared__ char lds[];  // set s at s*65536: [A 32K][B 32K]
  const int t = threadIdx.x;
  const int l = t & 63;
  const int w = t >> 6;
  const int wm = w >> 2;       // 0..1
  const int wn = w & 3;        // 0..3

  const int wgid = blockIdx.x;            // 1488 = 8 x 186
  const int xcd  = wgid & 7;
  const int work = xcd * 186 + (wgid >> 3);
  const int mt = work & 3;
  const int nt = work >> 2;
  const int n0 = nt * 256;

  const char* asrc = Abuf + (size_t)mt * (12 * TILE_B);

  // B staging role: thread owns col sn (0..255), k-rows kg*32..+31
  const int sn = t & 255;
  const int kg = t >> 8;       // 0..1
  const int gn = n0 + sn;
  const bool valid = gn < NCOLS;

  float br0[32], br1[32];

#define AGLD(s, ksi)                                                         \
  {                                                                          \
    _Pragma("unroll") for (int kk = 0; kk < 4; ++kk)                         \
      GLOAD16(asrc + (ksi)*TILE_B + kk*8192 + t*16,                          \
              lds + (s)*65536 + kk*8192 + w*1024);                           \
  }

#define BLOAD(br, ksi)                                                       \
  {                                                                          \
    const float* p = Wrev + (size_t)((ksi)*64 + kg*32) * NCOLS + gn;         \
    _Pragma("unroll") for (int j = 0; j < 32; ++j)                           \
      br[j] = valid ? p[(size_t)j * NCOLS] : 0.0f;                           \
  }

#define BSTORE(br, s)                                                        \
  {                                                                          \
    _Pragma("unroll") for (int c = 0; c < 2; ++c) {                          \
      u32x4 u0, u1;                                                          \
      _Pragma("unroll") for (int j = 0; j < 4; ++j) {                        \
        u0[j] = pack2(br[c*16 + 2*j],     br[c*16 + 2*j + 1]);               \
        u1[j] = pack2(br[c*16 + 8 + 2*j], br[c*16 + 9 + 2*j]);               \
      }                                                                      \
      char* bb = lds + (s)*65536 + 32768 + (kg*2 + c)*8192 + (sn>>5)*1024;   \
      *(u32x4*)(bb + (sn & 31)*16) = u0;                                     \
      *(u32x4*)(bb + ((sn & 31) + 32)*16) = u1;                              \
    }                                                                        \
  }

#define COMPUTE(cs)                                                          \
  {                                                                          \
    const char* aw = lds + (cs)*65536 + (wm*4)*1024 + l*16;                  \
    const char* bw = lds + (cs)*65536 + 32768 + (wn*2)*1024 + l*16;          \
    _Pragma("unroll") for (int p = 0; p < 4; ++p) {                          \
      bf16x8 a[4], b[2];                                                     \
      _Pragma("unroll") for (int mr = 0; mr < 4; ++mr)                       \
        a[mr] = *(const bf16x8*)(aw + p*8192 + mr*1024);                     \
      _Pragma("unroll") for (int nr = 0; nr < 2; ++nr)                       \
        b[nr] = *(const bf16x8*)(bw + p*8192 + nr*1024);                     \
      __builtin_amdgcn_s_setprio(1);                                         \
      _Pragma("unroll") for (int mr = 0; mr < 4; ++mr)                       \
        _Pragma("unroll") for (int nr = 0; nr < 2; ++nr)                     \
          acc[mr][nr] = __builtin_amdgcn_mfma_f32_32x32x16_bf16(             \
              a[mr], b[nr], acc[mr][nr], 0, 0, 0);                           \
      __builtin_amdgcn_s_setprio(0);                                         \
    }                                                                        \
  }

  // one full pipelined step: compute set cs / tile TT; prep set cs^1
#define STEP(cs, TT, brCur, brNext)                                          \
  {                                                                          \
    if ((TT) + 1 < 12) AGLD((cs) ^ 1, (TT) + 1);       /* oldest in queue */ \
    if ((TT) + 2 < 12) BLOAD(brNext, (TT) + 2);                              \
    __builtin_amdgcn_sched_barrier(0);                                       \
    COMPUTE(cs);                                                             \
    __builtin_amdgcn_sched_barrier(0);                                       \
    if ((TT) + 1 < 12) {                                                     \
      BSTORE(brCur, (cs) ^ 1);         /* brCur loaded a full step ago */    \
      asm volatile("s_waitcnt lgkmcnt(0)" ::: "memory");                     \
      if ((TT) + 2 < 12) asm volatile("s_waitcnt vmcnt(32)" ::: "memory");   \
      else               asm volatile("s_waitcnt vmcnt(0)" ::: "memory");    \
      __builtin_amdgcn_sched_barrier(0);                                     \
      __builtin_amdgcn_s_barrier();                                          \
    }                                                                        \
  }

  // prologue: tile 0 -> set 0; preload B(1) into br0
  AGLD(0, 0);
  BLOAD(br0, 0);
  BSTORE(br0, 0);   // compiler waits br0 (drains A(0) too — older)
  BLOAD(br0, 1);
  asm volatile("s_waitcnt lgkmcnt(0)" ::: "memory");
  __builtin_amdgcn_sched_barrier(0);
  __builtin_amdgcn_s_barrier();

  f32x16 acc[4][2] = {};

#pragma unroll
  for (int Ti = 0; Ti < 6; ++Ti) {
    STEP(0, 2 * Ti,     br0, br1);
    STEP(1, 2 * Ti + 1, br1, br0);
  }
#undef STEP
#undef COMPUTE
#undef AGLD
#undef BLOAD
#undef BSTORE

  // epilogue: C layout col=lane&31, row=(reg&3)+8*(reg>>2)+4*(lane>>5)
  const int lh = l >> 5;
#pragma unroll
  for (int nr = 0; nr < 2; ++nr) {
    const int gc = n0 + wn * 64 + nr * 32 + (l & 31);
    if (gc < NCOLS) {
#pragma unroll
      for (int mr = 0; mr < 4; ++mr)
#pragma unroll
        for (int reg = 0; reg < 16; ++reg) {
          const int row = mt * 256 + wm * 128 + mr * 32 +
                          (reg & 3) + 8 * (reg >> 2) + 4 * lh;
          out[(size_t)row * NCOLS + gc] = acc[mr][nr][reg];
        }
    }
  }
}

extern "C" void kernel_launch(void* const* d_in, const int* in_sizes, int n_in,
                              void* d_out, int out_size, void* d_ws, size_t ws_size,
                              hipStream_t stream) {
  const int*   ids       = (const int*)d_in[0];
  const float* W_emb     = (const float*)d_in[1];
  const float* W_rev     = (const float*)d_in[2];
  const float* padding   = (const float*)d_in[3];
  const int*   syn_table = (const int*)d_in[4];
  const int*   syn_mask  = (const int*)d_in[5];
  float* out = (float*)d_out;
  char*  ws  = (char*)d_ws;

  // A tiles in ws[0, 1.5MB); conv pass deleted
  hipLaunchKernelGGL(emb_kernel, dim3(NROWS), dim3(256), 0, stream,
                     ids, W_emb, padding, syn_table, syn_mask, ws);

  // 1488 blocks: 4 m-tiles x 372 n-tiles = 8 XCDs x 186 (bijective)
  hipLaunchKernelGGL(gemm_fused, dim3(4 * NT256), dim3(512), 131072, stream,
                     W_rev, ws, out);
}

// Round 23
// 328.196 us; speedup vs baseline: 1.1735x; 1.0019x over previous
//
#include <hip/hip_runtime.h>
#include <stdint.h>

#define EFFECT_DIM 758
#define ADD_DIM 10
#define EMBED_DIM 768
#define NCOLS 95000
#define NSYN 8
#define NROWS 1024
#define NT256 372            // ceil(95000/256)
#define TILE_B 32768         // 256x64 bf16 A tile, fragment-ordered

typedef __attribute__((ext_vector_type(8))) __bf16 bf16x8;
typedef __attribute__((ext_vector_type(16))) float f32x16;
typedef __attribute__((ext_vector_type(4))) uint32_t u32x4;

// Fragment order: tile = [kk 0..3][grp 0..7][lane 0..63] x 16B.
// frag(kk,grp) = 1KB; lane = (row&31) + (khalf8<<5); 16B = 8 consecutive k.
// ds_read_b128 + per-n (1n/thread) ds_write: 0 bank conflicts (R10-R22).
// R23 = R16 schedule at BK=32 -> 64KB LDS -> 2 blocks/CU (cross-block
// overlap hides barrier drains; the R2/R5 occupancy x R16 schedule combo).

static __device__ __forceinline__ uint32_t pack2(float a, float b) {
  uint32_t r;
  asm("v_cvt_pk_bf16_f32 %0, %1, %2" : "=v"(r) : "v"(a), "v"(b));
  return r;
}

#define GLOAD16(src, dst)                                                   \
  __builtin_amdgcn_global_load_lds(                                         \
      (const __attribute__((address_space(1))) uint32_t*)(src),             \
      (__attribute__((address_space(3))) uint32_t*)(dst), 16, 0, 0)

// ---------------------------------------------------------------------------
// Kernel 1: VirtualEmbedding -> bf16 A tiles (4 m-tiles x 12 ks), frag order.
// (verified R9-R22; layout untouched — gemm indexes 16KB halves)
// ---------------------------------------------------------------------------
__global__ __launch_bounds__(256) void emb_kernel(
    const int* __restrict__ ids, const float* __restrict__ W_emb,
    const float* __restrict__ padding, const int* __restrict__ syn_table,
    const int* __restrict__ syn_mask, char* __restrict__ ws)
{
  const int l = blockIdx.x;
  const int t = threadIdx.x;
  const int id = ids[l];
  int sid[NSYN];
  int msk[NSYN];
#pragma unroll
  for (int k = 0; k < NSYN; ++k) {
    sid[k] = syn_table[id * NSYN + k];
    msk[k] = syn_mask[id * NSYN + k];
  }

  double p[9] = {0, 0, 0, 0, 0, 0, 0, 0, 0};
  for (int d = t; d < EFFECT_DIM; d += 256) {
    p[0] += (double)W_emb[(size_t)id * EFFECT_DIM + d];
#pragma unroll
    for (int k = 0; k < NSYN; ++k)
      p[k + 1] += (double)W_emb[(size_t)sid[k] * EFFECT_DIM + d];
  }

  __shared__ double s_red[9][4];
  const int w = t >> 6;
#pragma unroll
  for (int k = 0; k < 9; ++k) {
    double v = p[k];
#pragma unroll
    for (int off = 32; off > 0; off >>= 1) v += __shfl_down(v, off, 64);
    if ((t & 63) == 0) s_red[k][w] = v;
  }
  __syncthreads();

  const double isum = s_red[0][0] + s_red[0][1] + s_red[0][2] + s_red[0][3];
  float coef[NSYN];
#pragma unroll
  for (int k = 0; k < NSYN; ++k) {
    double ss = s_red[k + 1][0] + s_red[k + 1][1] + s_red[k + 1][2] + s_red[k + 1][3];
    coef[k] = msk[k] ? (float)(isum / ss) : 0.0f;
  }

  const int r = l & 255;
  char* wbase = ws + (size_t)(l >> 8) * (12 * TILE_B);

  for (int j = t; j < 384; j += 256) {
    const int d0 = 2 * j;
    float v0, v1;
    if (d0 < EFFECT_DIM) {
      const float* bp = W_emb + (size_t)id * EFFECT_DIM + d0;
      v0 = bp[0];
      v1 = bp[1];
#pragma unroll
      for (int k = 0; k < NSYN; ++k) {
        const float* sp = W_emb + (size_t)sid[k] * EFFECT_DIM + d0;
        v0 = fmaf(coef[k], sp[0], v0);
        v1 = fmaf(coef[k], sp[1], v1);
      }
    } else {
      v0 = padding[l * ADD_DIM + (d0 - EFFECT_DIM)];
      v1 = padding[l * ADD_DIM + (d0 + 1 - EFFECT_DIM)];
    }
    const int ks   = j >> 5;
    const int jl   = j & 31;
    const int kk   = jl >> 3;
    const int byte = (jl & 7) * 4;
    const int lane = (r & 31) + ((byte >> 4) << 5);
    *(uint32_t*)(wbase + ks * TILE_B + kk * 8192 + (r >> 5) * 1024 +
                 lane * 16 + (byte & 15)) = pack2(v0, v1);
  }
}

// ---------------------------------------------------------------------------
// Kernel 2 (R23): 256x256 tile, BK=32 (24 K-steps), 512 thr, 8 waves
// (2m x 4n), wave 128x64, acc[4][2]. LDS 64KB = 2 sets x [A 16K][B 16K]
// -> 2 blocks/CU. Per K-step s (computing set cs = s&1):
//   AGLD(cs^1, s+1)          // 2 gload_lds (16KB half-tile), OLDEST in queue
//   BLOAD(brNext, s+2)       // 16 f32 loads, stay in flight 2 steps
//   2 x {6 ds_read_b128 + 8 MFMA (setprio)}
//   BSTORE(brCur = B(s+1))   // loaded a FULL step ago -> retired, no stall
//   lgkmcnt(0); vmcnt(16)    // A(s+1) confirmed (older), B(s+2) in flight
//   s_barrier
// A source: step s reads bytes [(s&1)*16384, +16K) of ws tile (s>>1)
// (contiguous in the kk-major frag order). T1 remap 1488 = 8 x 186.
// ---------------------------------------------------------------------------
__global__ __launch_bounds__(512, 2) void gemm_fused(
    const float* __restrict__ Wrev, const char* __restrict__ Abuf,
    float* __restrict__ out)
{
  extern __shared__ char lds[];  // set s at s*32768: [A 16K][B 16K]
  const int t = threadIdx.x;
  const int l = t & 63;
  const int w = t >> 6;
  const int wm = w >> 2;       // 0..1
  const int wn = w & 3;        // 0..3

  const int wgid = blockIdx.x;            // 1488 = 8 x 186
  const int xcd  = wgid & 7;
  const int work = xcd * 186 + (wgid >> 3);
  const int mt = work & 3;
  const int nt = work >> 2;
  const int n0 = nt * 256;

  const char* asrc = Abuf + (size_t)mt * (12 * TILE_B);

  // B staging role: thread owns col sn (0..255), k-rows kg*16..+15 of BK=32
  const int sn = t & 255;
  const int kg = t >> 8;       // 0..1
  const int gn = n0 + sn;
  const bool valid = gn < NCOLS;

  float br0[16], br1[16];

  // step s: A half-tile = ws tile (s>>1), byte half (s&1)*16384
#define AGLD(dst_s, s_)                                                      \
  {                                                                          \
    const char* sa = asrc + ((s_) >> 1) * TILE_B + ((s_) & 1) * 16384;       \
    GLOAD16(sa + t * 16, lds + (dst_s)*32768 + w * 1024);                    \
    GLOAD16(sa + 8192 + t * 16, lds + (dst_s)*32768 + 8192 + w * 1024);      \
  }

#define BLOAD(br, s_)                                                        \
  {                                                                          \
    const float* p = Wrev + (size_t)((s_)*32 + kg * 16) * NCOLS + gn;        \
    _Pragma("unroll") for (int j = 0; j < 16; ++j)                           \
      br[j] = valid ? p[(size_t)j * NCOLS] : 0.0f;                           \
  }

#define BSTORE(br, dst_s)                                                    \
  {                                                                          \
    _Pragma("unroll") for (int kh = 0; kh < 2; ++kh) {                       \
      u32x4 u;                                                               \
      _Pragma("unroll") for (int j = 0; j < 4; ++j)                          \
        u[j] = pack2(br[kh * 8 + 2 * j], br[kh * 8 + 2 * j + 1]);            \
      *(u32x4*)(lds + (dst_s)*32768 + 16384 + kg * 8192 + (sn >> 5) * 1024 + \
                ((sn & 31) + (kh << 5)) * 16) = u;                           \
    }                                                                        \
  }

#define COMPUTE(cs)                                                          \
  {                                                                          \
    const char* aw = lds + (cs)*32768 + (wm * 4) * 1024 + l * 16;            \
    const char* bw = lds + (cs)*32768 + 16384 + (wn * 2) * 1024 + l * 16;    \
    _Pragma("unroll") for (int p = 0; p < 2; ++p) {                          \
      bf16x8 a[4], b[2];                                                     \
      _Pragma("unroll") for (int mr = 0; mr < 4; ++mr)                       \
        a[mr] = *(const bf16x8*)(aw + p * 8192 + mr * 1024);                 \
      _Pragma("unroll") for (int nr = 0; nr < 2; ++nr)                       \
        b[nr] = *(const bf16x8*)(bw + p * 8192 + nr * 1024);                 \
      __builtin_amdgcn_s_setprio(1);                                         \
      _Pragma("unroll") for (int mr = 0; mr < 4; ++mr)                       \
        _Pragma("unroll") for (int nr = 0; nr < 2; ++nr)                     \
          acc[mr][nr] = __builtin_amdgcn_mfma_f32_32x32x16_bf16(             \
              a[mr], b[nr], acc[mr][nr], 0, 0, 0);                           \
      __builtin_amdgcn_s_setprio(0);                                         \
    }                                                                        \
  }

  // one pipelined step: compute set cs / step SS; prep set cs^1
#define STEP(cs, SS, brCur, brNext)                                          \
  {                                                                          \
    if ((SS) + 1 < 24) AGLD((cs) ^ 1, (SS) + 1);       /* oldest in queue */ \
    if ((SS) + 2 < 24) BLOAD(brNext, (SS) + 2);                              \
    __builtin_amdgcn_sched_barrier(0);                                       \
    COMPUTE(cs);                                                             \
    __builtin_amdgcn_sched_barrier(0);                                       \
    if ((SS) + 1 < 24) {                                                     \
      BSTORE(brCur, (cs) ^ 1);         /* brCur loaded a full step ago */    \
      asm volatile("s_waitcnt lgkmcnt(0)" ::: "memory");                     \
      if ((SS) + 2 < 24) asm volatile("s_waitcnt vmcnt(16)" ::: "memory");   \
      else               asm volatile("s_waitcnt vmcnt(0)" ::: "memory");    \
      __builtin_amdgcn_sched_barrier(0);                                     \
      __builtin_amdgcn_s_barrier();                                          \
    }                                                                        \
  }

  // prologue: step 0 -> set 0; preload B(1) into br0
  AGLD(0, 0);
  BLOAD(br0, 0);
  BSTORE(br0, 0);   // compiler waits br0 (drains A(0) too — older)
  BLOAD(br0, 1);
  asm volatile("s_waitcnt lgkmcnt(0)" ::: "memory");
  __builtin_amdgcn_sched_barrier(0);
  __builtin_amdgcn_s_barrier();

  f32x16 acc[4][2] = {};

#pragma unroll
  for (int Si = 0; Si < 12; ++Si) {
    STEP(0, 2 * Si,     br0, br1);
    STEP(1, 2 * Si + 1, br1, br0);
  }
#undef STEP
#undef COMPUTE
#undef AGLD
#undef BLOAD
#undef BSTORE

  // epilogue: C layout col=lane&31, row=(reg&3)+8*(reg>>2)+4*(lane>>5)
  const int lh = l >> 5;
#pragma unroll
  for (int nr = 0; nr < 2; ++nr) {
    const int gc = n0 + wn * 64 + nr * 32 + (l & 31);
    if (gc < NCOLS) {
#pragma unroll
      for (int mr = 0; mr < 4; ++mr)
#pragma unroll
        for (int reg = 0; reg < 16; ++reg) {
          const int row = mt * 256 + wm * 128 + mr * 32 +
                          (reg & 3) + 8 * (reg >> 2) + 4 * lh;
          out[(size_t)row * NCOLS + gc] = acc[mr][nr][reg];
        }
    }
  }
}

extern "C" void kernel_launch(void* const* d_in, const int* in_sizes, int n_in,
                              void* d_out, int out_size, void* d_ws, size_t ws_size,
                              hipStream_t stream) {
  const int*   ids       = (const int*)d_in[0];
  const float* W_emb     = (const float*)d_in[1];
  const float* W_rev     = (const float*)d_in[2];
  const float* padding   = (const float*)d_in[3];
  const int*   syn_table = (const int*)d_in[4];
  const int*   syn_mask  = (const int*)d_in[5];
  float* out = (float*)d_out;
  char*  ws  = (char*)d_ws;

  // A tiles in ws[0, 1.5MB); conv pass deleted
  hipLaunchKernelGGL(emb_kernel, dim3(NROWS), dim3(256), 0, stream,
                     ids, W_emb, padding, syn_table, syn_mask, ws);

  // 1488 blocks: 4 m-tiles x 372 n-tiles = 8 XCDs x 186 (bijective);
  // 64KB dynamic LDS -> 2 blocks/CU
  hipLaunchKernelGGL(gemm_fused, dim3(4 * NT256), dim3(512), 65536, stream,
                     W_rev, ws, out);
}

// Round 24
// 326.438 us; speedup vs baseline: 1.1798x; 1.0054x over previous
//
#include <hip/hip_runtime.h>
#include <stdint.h>

#define EFFECT_DIM 758
#define ADD_DIM 10
#define EMBED_DIM 768
#define NCOLS 95000
#define NSYN 8
#define NROWS 1024
#define NT256 372            // ceil(95000/256)
#define TILE_B 32768         // 256x64 bf16 A tile, fragment-ordered

typedef __attribute__((ext_vector_type(8))) __bf16 bf16x8;
typedef __attribute__((ext_vector_type(16))) float f32x16;
typedef __attribute__((ext_vector_type(4))) uint32_t u32x4;

// Fragment order: tile = [kk 0..3][grp 0..7][lane 0..63] x 16B.
// frag(kk,grp) = 1KB; lane = (row&31) + (khalf8<<5); 16B = 8 consecutive k.
// ds_read_b128 + per-n (1n/thread) ds_write: 0 bank conflicts (R10-R23).
// R24 = R23 with STATIC 64KB LDS (dynamic-LDS launches measured 22% occ at
// both 128KB and 64KB; static 64KB measured 41% in R5/R6 -> 2 blocks/CU).

static __device__ __forceinline__ uint32_t pack2(float a, float b) {
  uint32_t r;
  asm("v_cvt_pk_bf16_f32 %0, %1, %2" : "=v"(r) : "v"(a), "v"(b));
  return r;
}

#define GLOAD16(src, dst)                                                   \
  __builtin_amdgcn_global_load_lds(                                         \
      (const __attribute__((address_space(1))) uint32_t*)(src),             \
      (__attribute__((address_space(3))) uint32_t*)(dst), 16, 0, 0)

// ---------------------------------------------------------------------------
// Kernel 1: VirtualEmbedding -> bf16 A tiles (4 m-tiles x 12 ks), frag order.
// (verified R9-R23; layout untouched — gemm indexes 16KB halves)
// ---------------------------------------------------------------------------
__global__ __launch_bounds__(256) void emb_kernel(
    const int* __restrict__ ids, const float* __restrict__ W_emb,
    const float* __restrict__ padding, const int* __restrict__ syn_table,
    const int* __restrict__ syn_mask, char* __restrict__ ws)
{
  const int l = blockIdx.x;
  const int t = threadIdx.x;
  const int id = ids[l];
  int sid[NSYN];
  int msk[NSYN];
#pragma unroll
  for (int k = 0; k < NSYN; ++k) {
    sid[k] = syn_table[id * NSYN + k];
    msk[k] = syn_mask[id * NSYN + k];
  }

  double p[9] = {0, 0, 0, 0, 0, 0, 0, 0, 0};
  for (int d = t; d < EFFECT_DIM; d += 256) {
    p[0] += (double)W_emb[(size_t)id * EFFECT_DIM + d];
#pragma unroll
    for (int k = 0; k < NSYN; ++k)
      p[k + 1] += (double)W_emb[(size_t)sid[k] * EFFECT_DIM + d];
  }

  __shared__ double s_red[9][4];
  const int w = t >> 6;
#pragma unroll
  for (int k = 0; k < 9; ++k) {
    double v = p[k];
#pragma unroll
    for (int off = 32; off > 0; off >>= 1) v += __shfl_down(v, off, 64);
    if ((t & 63) == 0) s_red[k][w] = v;
  }
  __syncthreads();

  const double isum = s_red[0][0] + s_red[0][1] + s_red[0][2] + s_red[0][3];
  float coef[NSYN];
#pragma unroll
  for (int k = 0; k < NSYN; ++k) {
    double ss = s_red[k + 1][0] + s_red[k + 1][1] + s_red[k + 1][2] + s_red[k + 1][3];
    coef[k] = msk[k] ? (float)(isum / ss) : 0.0f;
  }

  const int r = l & 255;
  char* wbase = ws + (size_t)(l >> 8) * (12 * TILE_B);

  for (int j = t; j < 384; j += 256) {
    const int d0 = 2 * j;
    float v0, v1;
    if (d0 < EFFECT_DIM) {
      const float* bp = W_emb + (size_t)id * EFFECT_DIM + d0;
      v0 = bp[0];
      v1 = bp[1];
#pragma unroll
      for (int k = 0; k < NSYN; ++k) {
        const float* sp = W_emb + (size_t)sid[k] * EFFECT_DIM + d0;
        v0 = fmaf(coef[k], sp[0], v0);
        v1 = fmaf(coef[k], sp[1], v1);
      }
    } else {
      v0 = padding[l * ADD_DIM + (d0 - EFFECT_DIM)];
      v1 = padding[l * ADD_DIM + (d0 + 1 - EFFECT_DIM)];
    }
    const int ks   = j >> 5;
    const int jl   = j & 31;
    const int kk   = jl >> 3;
    const int byte = (jl & 7) * 4;
    const int lane = (r & 31) + ((byte >> 4) << 5);
    *(uint32_t*)(wbase + ks * TILE_B + kk * 8192 + (r >> 5) * 1024 +
                 lane * 16 + (byte & 15)) = pack2(v0, v1);
  }
}

// ---------------------------------------------------------------------------
// Kernel 2 (R24 = R23 with static 64KB LDS): 256x256 tile, BK=32 (24 steps),
// 512 thr, 8 waves (2m x 4n), wave 128x64, acc[4][2]. LDS 64KB = 2 sets x
// [A 16K][B 16K] -> target 2 blocks/CU. Per K-step s (set cs = s&1):
//   AGLD(cs^1, s+1)          // 2 gload_lds (16KB half-tile), OLDEST in queue
//   BLOAD(brNext, s+2)       // 16 f32 loads, stay in flight 2 steps
//   2 x {6 ds_read_b128 + 8 MFMA (setprio)}
//   BSTORE(brCur = B(s+1))   // loaded a FULL step ago -> retired, no stall
//   lgkmcnt(0); vmcnt(16)    // A(s+1) confirmed (older), B(s+2) in flight
//   s_barrier
// A source: step s reads bytes [(s&1)*16384, +16K) of ws tile (s>>1).
// T1 remap 1488 = 8 x 186 (bijective).
// ---------------------------------------------------------------------------
__global__ __launch_bounds__(512, 2) void gemm_fused(
    const float* __restrict__ Wrev, const char* __restrict__ Abuf,
    float* __restrict__ out)
{
  __shared__ char lds[65536];  // STATIC: set s at s*32768: [A 16K][B 16K]
  const int t = threadIdx.x;
  const int l = t & 63;
  const int w = t >> 6;
  const int wm = w >> 2;       // 0..1
  const int wn = w & 3;        // 0..3

  const int wgid = blockIdx.x;            // 1488 = 8 x 186
  const int xcd  = wgid & 7;
  const int work = xcd * 186 + (wgid >> 3);
  const int mt = work & 3;
  const int nt = work >> 2;
  const int n0 = nt * 256;

  const char* asrc = Abuf + (size_t)mt * (12 * TILE_B);

  // B staging role: thread owns col sn (0..255), k-rows kg*16..+15 of BK=32
  const int sn = t & 255;
  const int kg = t >> 8;       // 0..1
  const int gn = n0 + sn;
  const bool valid = gn < NCOLS;

  float br0[16], br1[16];

  // step s: A half-tile = ws tile (s>>1), byte half (s&1)*16384
#define AGLD(dst_s, s_)                                                      \
  {                                                                          \
    const char* sa = asrc + ((s_) >> 1) * TILE_B + ((s_) & 1) * 16384;       \
    GLOAD16(sa + t * 16, lds + (dst_s)*32768 + w * 1024);                    \
    GLOAD16(sa + 8192 + t * 16, lds + (dst_s)*32768 + 8192 + w * 1024);      \
  }

#define BLOAD(br, s_)                                                        \
  {                                                                          \
    const float* p = Wrev + (size_t)((s_)*32 + kg * 16) * NCOLS + gn;        \
    _Pragma("unroll") for (int j = 0; j < 16; ++j)                           \
      br[j] = valid ? p[(size_t)j * NCOLS] : 0.0f;                           \
  }

#define BSTORE(br, dst_s)                                                    \
  {                                                                          \
    _Pragma("unroll") for (int kh = 0; kh < 2; ++kh) {                       \
      u32x4 u;                                                               \
      _Pragma("unroll") for (int j = 0; j < 4; ++j)                          \
        u[j] = pack2(br[kh * 8 + 2 * j], br[kh * 8 + 2 * j + 1]);            \
      *(u32x4*)(lds + (dst_s)*32768 + 16384 + kg * 8192 + (sn >> 5) * 1024 + \
                ((sn & 31) + (kh << 5)) * 16) = u;                           \
    }                                                                        \
  }

#define COMPUTE(cs)                                                          \
  {                                                                          \
    const char* aw = lds + (cs)*32768 + (wm * 4) * 1024 + l * 16;            \
    const char* bw = lds + (cs)*32768 + 16384 + (wn * 2) * 1024 + l * 16;    \
    _Pragma("unroll") for (int p = 0; p < 2; ++p) {                          \
      bf16x8 a[4], b[2];                                                     \
      _Pragma("unroll") for (int mr = 0; mr < 4; ++mr)                       \
        a[mr] = *(const bf16x8*)(aw + p * 8192 + mr * 1024);                 \
      _Pragma("unroll") for (int nr = 0; nr < 2; ++nr)                       \
        b[nr] = *(const bf16x8*)(bw + p * 8192 + nr * 1024);                 \
      __builtin_amdgcn_s_setprio(1);                                         \
      _Pragma("unroll") for (int mr = 0; mr < 4; ++mr)                       \
        _Pragma("unroll") for (int nr = 0; nr < 2; ++nr)                     \
          acc[mr][nr] = __builtin_amdgcn_mfma_f32_32x32x16_bf16(             \
              a[mr], b[nr], acc[mr][nr], 0, 0, 0);                           \
      __builtin_amdgcn_s_setprio(0);                                         \
    }                                                                        \
  }

  // one pipelined step: compute set cs / step SS; prep set cs^1
#define STEP(cs, SS, brCur, brNext)                                          \
  {                                                                          \
    if ((SS) + 1 < 24) AGLD((cs) ^ 1, (SS) + 1);       /* oldest in queue */ \
    if ((SS) + 2 < 24) BLOAD(brNext, (SS) + 2);                              \
    __builtin_amdgcn_sched_barrier(0);                                       \
    COMPUTE(cs);                                                             \
    __builtin_amdgcn_sched_barrier(0);                                       \
    if ((SS) + 1 < 24) {                                                     \
      BSTORE(brCur, (cs) ^ 1);         /* brCur loaded a full step ago */    \
      asm volatile("s_waitcnt lgkmcnt(0)" ::: "memory");                     \
      if ((SS) + 2 < 24) asm volatile("s_waitcnt vmcnt(16)" ::: "memory");   \
      else               asm volatile("s_waitcnt vmcnt(0)" ::: "memory");    \
      __builtin_amdgcn_sched_barrier(0);                                     \
      __builtin_amdgcn_s_barrier();                                          \
    }                                                                        \
  }

  // prologue: step 0 -> set 0; preload B(1) into br0
  AGLD(0, 0);
  BLOAD(br0, 0);
  BSTORE(br0, 0);   // compiler waits br0 (drains A(0) too — older)
  BLOAD(br0, 1);
  asm volatile("s_waitcnt lgkmcnt(0)" ::: "memory");
  __builtin_amdgcn_sched_barrier(0);
  __builtin_amdgcn_s_barrier();

  f32x16 acc[4][2] = {};

#pragma unroll
  for (int Si = 0; Si < 12; ++Si) {
    STEP(0, 2 * Si,     br0, br1);
    STEP(1, 2 * Si + 1, br1, br0);
  }
#undef STEP
#undef COMPUTE
#undef AGLD
#undef BLOAD
#undef BSTORE

  // epilogue: C layout col=lane&31, row=(reg&3)+8*(reg>>2)+4*(lane>>5)
  const int lh = l >> 5;
#pragma unroll
  for (int nr = 0; nr < 2; ++nr) {
    const int gc = n0 + wn * 64 + nr * 32 + (l & 31);
    if (gc < NCOLS) {
#pragma unroll
      for (int mr = 0; mr < 4; ++mr)
#pragma unroll
        for (int reg = 0; reg < 16; ++reg) {
          const int row = mt * 256 + wm * 128 + mr * 32 +
                          (reg & 3) + 8 * (reg >> 2) + 4 * lh;
          out[(size_t)row * NCOLS + gc] = acc[mr][nr][reg];
        }
    }
  }
}

extern "C" void kernel_launch(void* const* d_in, const int* in_sizes, int n_in,
                              void* d_out, int out_size, void* d_ws, size_t ws_size,
                              hipStream_t stream) {
  const int*   ids       = (const int*)d_in[0];
  const float* W_emb     = (const float*)d_in[1];
  const float* W_rev     = (const float*)d_in[2];
  const float* padding   = (const float*)d_in[3];
  const int*   syn_table = (const int*)d_in[4];
  const int*   syn_mask  = (const int*)d_in[5];
  float* out = (float*)d_out;
  char*  ws  = (char*)d_ws;

  // A tiles in ws[0, 1.5MB); conv pass deleted
  hipLaunchKernelGGL(emb_kernel, dim3(NROWS), dim3(256), 0, stream,
                     ids, W_emb, padding, syn_table, syn_mask, ws);

  // 1488 blocks: 4 m-tiles x 372 n-tiles = 8 XCDs x 186 (bijective);
  // static 64KB LDS -> 2 blocks/CU
  hipLaunchKernelGGL(gemm_fused, dim3(4 * NT256), dim3(512), 0, stream,
                     W_rev, ws, out);
}